// Round 3
// baseline (486.786 us; speedup 1.0000x reference)
//
#include <hip/hip_runtime.h>
#include <hip/hip_bf16.h>
#include <math.h>

#define HDIM 64
#define NN   100000
#define NE   1600000
#define TEMP 30.0f
#define LNEPS 1e-5f

typedef __attribute__((ext_vector_type(8))) short bf16x8;
typedef __attribute__((ext_vector_type(4))) float f32x4;

__device__ __forceinline__ short f2bf(float f) {
    __hip_bfloat16 b = __float2bfloat16(f);
    short s; __builtin_memcpy(&s, &b, 2); return s;
}
__device__ __forceinline__ unsigned pk2(float lo, float hi) {
    return (unsigned)(unsigned short)f2bf(lo) | ((unsigned)(unsigned short)f2bf(hi) << 16);
}
__device__ __forceinline__ float bf2f(unsigned u) {
    union { unsigned u; float f; } c; c.u = u << 16; return c.f;
}
__device__ __forceinline__ float sigmoidf_(float z) { return 1.0f / (1.0f + __expf(-z)); }

// ============ Pre kernel: per-NODE factorization of edge GEMM1 ============
// e_in @ We1 = h[dst] @ We1[0:64] + h[src] @ We1[64:128]
// Pt[n] = h[n] @ We1_top + be1 ; Pb[n] = h[n] @ We1_bot   (bf16 rows, 128 B)
extern "C" __global__ void __launch_bounds__(256, 2)
pre_kernel(const float* __restrict__ h,
           const float* __restrict__ We1, const float* __restrict__ be1,
           unsigned short* __restrict__ Pt, unsigned short* __restrict__ Pb)
{
    __shared__ float fx[4][1024];
    const int tid  = threadIdx.x;
    const int wib  = tid >> 6;
    const int lane = tid & 63;
    const int e = lane & 15, g = lane >> 4;
    float* fb = &fx[wib][0];
    const int se = ((e & 1) << 4) | ((e >> 1) & 3);

    bf16x8 At[4][2], Ab[4][2];
    f32x4 b1r[4];
    #pragma unroll
    for (int t = 0; t < 4; ++t) {
        #pragma unroll
        for (int ks = 0; ks < 2; ++ks) {
            bf16x8 a, b;
            #pragma unroll
            for (int j = 0; j < 8; ++j) {
                a[j] = f2bf(We1[(32 * ks + 8 * g + j) * 64 + 16 * t + e]);
                b[j] = f2bf(We1[(64 + 32 * ks + 8 * g + j) * 64 + 16 * t + e]);
            }
            At[t][ks] = a; Ab[t][ks] = b;
        }
        #pragma unroll
        for (int r = 0; r < 4; ++r) b1r[t][r] = be1[16 * t + 4 * g + r];
    }

    const int gwid = blockIdx.x * 4 + wib;
    const int nw   = gridDim.x * 4;

    for (int tile = gwid; tile < NN / 16; tile += nw) {
        const int node = tile * 16 + e;

        bf16x8 B[2];
        #pragma unroll
        for (int ks = 0; ks < 2; ++ks) {
            const float4* p = (const float4*)(h + (size_t)node * 64 + ks * 32 + 8 * g);
            const float4 f0 = p[0], f1 = p[1];
            bf16x8 b;
            b[0] = f2bf(f0.x); b[1] = f2bf(f0.y); b[2] = f2bf(f0.z); b[3] = f2bf(f0.w);
            b[4] = f2bf(f1.x); b[5] = f2bf(f1.y); b[6] = f2bf(f1.z); b[7] = f2bf(f1.w);
            B[ks] = b;
        }

        f32x4 aT[4], aB[4];
        #pragma unroll
        for (int t = 0; t < 4; ++t) {
            aT[t] = b1r[t];
            aB[t] = (f32x4){0.f, 0.f, 0.f, 0.f};
            #pragma unroll
            for (int ks = 0; ks < 2; ++ks) {
                aT[t] = __builtin_amdgcn_mfma_f32_16x16x32_bf16(At[t][ks], B[ks], aT[t], 0, 0, 0);
                aB[t] = __builtin_amdgcn_mfma_f32_16x16x32_bf16(Ab[t][ks], B[ks], aB[t], 0, 0, 0);
            }
        }

        #pragma unroll
        for (int t = 0; t < 4; ++t)
            #pragma unroll
            for (int r = 0; r < 4; ++r)
                fb[e * 64 + ((16 * t + 4 * g + r) ^ se)] = aT[t][r];
        #pragma unroll
        for (int q = 0; q < 2; ++q) {
            const int row = q * 8 + (lane >> 3);
            const int sr  = ((row & 1) << 4) | ((row >> 1) & 3);
            const int c0  = (lane & 7) * 8;
            uint4 o;
            o.x = pk2(fb[row * 64 + ((c0 + 0) ^ sr)], fb[row * 64 + ((c0 + 1) ^ sr)]);
            o.y = pk2(fb[row * 64 + ((c0 + 2) ^ sr)], fb[row * 64 + ((c0 + 3) ^ sr)]);
            o.z = pk2(fb[row * 64 + ((c0 + 4) ^ sr)], fb[row * 64 + ((c0 + 5) ^ sr)]);
            o.w = pk2(fb[row * 64 + ((c0 + 6) ^ sr)], fb[row * 64 + ((c0 + 7) ^ sr)]);
            *(uint4*)((char*)Pt + (size_t)tile * 2048 + q * 1024 + lane * 16) = o;
        }

        #pragma unroll
        for (int t = 0; t < 4; ++t)
            #pragma unroll
            for (int r = 0; r < 4; ++r)
                fb[e * 64 + ((16 * t + 4 * g + r) ^ se)] = aB[t][r];
        #pragma unroll
        for (int q = 0; q < 2; ++q) {
            const int row = q * 8 + (lane >> 3);
            const int sr  = ((row & 1) << 4) | ((row >> 1) & 3);
            const int c0  = (lane & 7) * 8;
            uint4 o;
            o.x = pk2(fb[row * 64 + ((c0 + 0) ^ sr)], fb[row * 64 + ((c0 + 1) ^ sr)]);
            o.y = pk2(fb[row * 64 + ((c0 + 2) ^ sr)], fb[row * 64 + ((c0 + 3) ^ sr)]);
            o.z = pk2(fb[row * 64 + ((c0 + 4) ^ sr)], fb[row * 64 + ((c0 + 5) ^ sr)]);
            o.w = pk2(fb[row * 64 + ((c0 + 6) ^ sr)], fb[row * 64 + ((c0 + 7) ^ sr)]);
            *(uint4*)((char*)Pb + (size_t)tile * 2048 + q * 1024 + lane * 16) = o;
        }
    }
}

// ============ Counting-sort of edges by dst ============
extern "C" __global__ void __launch_bounds__(256)
hist_kernel(const int* __restrict__ ei, int* __restrict__ cnt)
{
    const int stride = gridDim.x * 256;
    for (int i = blockIdx.x * 256 + threadIdx.x; i < NE; i += stride)
        atomicAdd(&cnt[ei[NE + i]], 1);
}

extern "C" __global__ void __launch_bounds__(1024)
scan_kernel(const int* __restrict__ cnt, int* __restrict__ cur)
{
    __shared__ int part[1024];
    const int t = threadIdx.x;
    const int CH = (NN + 1023) >> 10;          // 98
    const int i0 = t * CH;
    const int i1 = (i0 + CH < NN) ? i0 + CH : NN;
    int s = 0;
    for (int i = i0; i < i1; ++i) s += cnt[i];
    part[t] = s;
    __syncthreads();
    for (int off = 1; off < 1024; off <<= 1) {
        int v = (t >= off) ? part[t - off] : 0;
        __syncthreads();
        part[t] += v;
        __syncthreads();
    }
    int run = part[t] - s;                     // exclusive prefix for this thread
    for (int i = i0; i < i1; ++i) { cur[i] = run; run += cnt[i]; }
}

extern "C" __global__ void __launch_bounds__(256)
scatter_kernel(const int* __restrict__ ei, int* __restrict__ cur,
               int2* __restrict__ spair)
{
    const int stride = gridDim.x * 256;
    for (int i = blockIdx.x * 256 + threadIdx.x; i < NE; i += stride) {
        const int s = ei[i];
        const int d = ei[NE + i];
        const int pos = atomicAdd(&cur[d], 1);
        spair[pos] = make_int2(s, d);
    }
}

// ============ Edge kernel (sorted): GEMM2 + gate + segmented reg-accumulate ====
// Edges sorted by dst; each wave walks a CONTIGUOUS chunk of 16-edge tiles,
// accumulating each node's output row in a register (channel = lane) and
// flushing ONE atomic row-write per distinct node (~106K flushes vs 1.6M).
extern "C" __global__ void __launch_bounds__(256, 2)
edge_kernel_sorted(const unsigned short* __restrict__ Pt, const unsigned short* __restrict__ Pb,
                   const float* __restrict__ x, const int2* __restrict__ spair,
                   const float* __restrict__ We2, const float* __restrict__ be2,
                   const float* __restrict__ Winf, const float* __restrict__ binf,
                   float* __restrict__ mi)
{
    __shared__ float fx[4][1024];
    const int tid  = threadIdx.x;
    const int wib  = tid >> 6;
    const int lane = tid & 63;
    const int e = lane & 15, g = lane >> 4;
    float* fb = &fx[wib][0];
    const int se = ((e & 1) << 4) | ((e >> 1) & 3);

    bf16x8 A2[4][2];
    f32x4 b2r[4], wir[4];
    #pragma unroll
    for (int t = 0; t < 4; ++t) {
        #pragma unroll
        for (int ks = 0; ks < 2; ++ks) {
            bf16x8 a;
            #pragma unroll
            for (int j = 0; j < 8; ++j)
                a[j] = f2bf(We2[(32 * ks + 8 * g + j) * 64 + 16 * t + e]);
            A2[t][ks] = a;
        }
        #pragma unroll
        for (int r = 0; r < 4; ++r) {
            b2r[t][r] = be2[16 * t + 4 * g + r];
            wir[t][r] = Winf[16 * t + 4 * g + r];
        }
    }
    const float binf0 = binf[0];

    const int NT     = NE / 16;
    const int nwaves = gridDim.x * 4;
    const int gwid   = blockIdx.x * 4 + wib;
    const int chunk  = (NT + nwaves - 1) / nwaves;
    const int t0 = gwid * chunk;
    const int t1 = (t0 + chunk < NT) ? t0 + chunk : NT;

    float racc  = 0.f;   // running row accumulator, channel = lane
    int   rrow  = -1;    // wave-uniform current node id

    for (int tile = t0; tile < t1; ++tile) {
        const int eid = tile * 16 + e;
        const int2 sd = spair[eid];
        const int sN = sd.x;
        const int dN = sd.y;

        const float dx = x[dN * 3 + 0] - x[sN * 3 + 0];
        const float dy = x[dN * 3 + 1] - x[sN * 3 + 1];
        const float dz = x[dN * 3 + 2] - x[sN * 3 + 2];
        const float dsq = dx * dx + dy * dy + dz * dz;
        const float edis = sigmoidf_(TEMP / (sqrtf(dsq) + 1e-8f));

        // ---- B2 frags: relu(Pt[dst] + Pb[src]) on k=32ks+8g+{0..7} ----
        bf16x8 B2[2];
        #pragma unroll
        for (int ks = 0; ks < 2; ++ks) {
            const uint4 ut = *(const uint4*)(Pt + (size_t)dN * 64 + 32 * ks + 8 * g);
            const uint4 ub = *(const uint4*)(Pb + (size_t)sN * 64 + 32 * ks + 8 * g);
            bf16x8 b;
            unsigned tw, bw;
            tw = ut.x; bw = ub.x;
            b[0] = f2bf(fmaxf(bf2f(tw & 0xffffu) + bf2f(bw & 0xffffu), 0.f));
            b[1] = f2bf(fmaxf(bf2f(tw >> 16)     + bf2f(bw >> 16),     0.f));
            tw = ut.y; bw = ub.y;
            b[2] = f2bf(fmaxf(bf2f(tw & 0xffffu) + bf2f(bw & 0xffffu), 0.f));
            b[3] = f2bf(fmaxf(bf2f(tw >> 16)     + bf2f(bw >> 16),     0.f));
            tw = ut.z; bw = ub.z;
            b[4] = f2bf(fmaxf(bf2f(tw & 0xffffu) + bf2f(bw & 0xffffu), 0.f));
            b[5] = f2bf(fmaxf(bf2f(tw >> 16)     + bf2f(bw >> 16),     0.f));
            tw = ut.w; bw = ub.w;
            b[6] = f2bf(fmaxf(bf2f(tw & 0xffffu) + bf2f(bw & 0xffffu), 0.f));
            b[7] = f2bf(fmaxf(bf2f(tw >> 16)     + bf2f(bw >> 16),     0.f));
            B2[ks] = b;
        }

        // ---- GEMM2 + bias ----
        f32x4 acc2[4];
        #pragma unroll
        for (int t = 0; t < 4; ++t) {
            acc2[t] = b2r[t];
            #pragma unroll
            for (int ks = 0; ks < 2; ++ks)
                acc2[t] = __builtin_amdgcn_mfma_f32_16x16x32_bf16(A2[t][ks], B2[ks], acc2[t], 0, 0, 0);
        }

        // ---- relu, edge_inf dot, gate ----
        float m[4][4];
        float p = 0.f;
        #pragma unroll
        for (int t = 0; t < 4; ++t)
            #pragma unroll
            for (int r = 0; r < 4; ++r) {
                m[t][r] = fmaxf(acc2[t][r], 0.f);
                p = fmaf(m[t][r], wir[t][r], p);
            }
        p += __shfl_xor(p, 16);
        p += __shfl_xor(p, 32);
        const float w = sigmoidf_((p + binf0) * edis);

        // ---- transpose m*w through LDS to [edge][channel] (bank-swizzled) ----
        #pragma unroll
        for (int t = 0; t < 4; ++t)
            #pragma unroll
            for (int r = 0; r < 4; ++r)
                fb[e * 64 + ((16 * t + 4 * g + r) ^ se)] = m[t][r] * w;

        // ---- segmented accumulate over sorted dst; flush once per run ----
        #pragma unroll
        for (int i = 0; i < 16; ++i) {
            const int row = __builtin_amdgcn_readlane(dN, i);   // wave-uniform (SGPR)
            const int si = ((i & 1) << 4) | ((i >> 1) & 3);
            const float v = fb[i * 64 + (lane ^ si)];
            if (row != rrow) {
                if (rrow >= 0) atomicAdd(mi + (size_t)rrow * 64 + lane, racc);
                rrow = row; racc = v;
            } else {
                racc += v;
            }
        }
    }
    if (rrow >= 0) atomicAdd(mi + (size_t)rrow * 64 + lane, racc);
}

// ============ Edge kernel (unsorted fallback, R2 path) ============
extern "C" __global__ void __launch_bounds__(256, 2)
edge_kernel_unsorted(const unsigned short* __restrict__ Pt, const unsigned short* __restrict__ Pb,
                     const float* __restrict__ x, const int* __restrict__ ei,
                     const float* __restrict__ We2, const float* __restrict__ be2,
                     const float* __restrict__ Winf, const float* __restrict__ binf,
                     float* __restrict__ mi)
{
    __shared__ float fx[4][1024];
    const int tid  = threadIdx.x;
    const int wib  = tid >> 6;
    const int lane = tid & 63;
    const int e = lane & 15, g = lane >> 4;
    float* fb = &fx[wib][0];
    const int se = ((e & 1) << 4) | ((e >> 1) & 3);

    bf16x8 A2[4][2];
    f32x4 b2r[4], wir[4];
    #pragma unroll
    for (int t = 0; t < 4; ++t) {
        #pragma unroll
        for (int ks = 0; ks < 2; ++ks) {
            bf16x8 a;
            #pragma unroll
            for (int j = 0; j < 8; ++j)
                a[j] = f2bf(We2[(32 * ks + 8 * g + j) * 64 + 16 * t + e]);
            A2[t][ks] = a;
        }
        #pragma unroll
        for (int r = 0; r < 4; ++r) {
            b2r[t][r] = be2[16 * t + 4 * g + r];
            wir[t][r] = Winf[16 * t + 4 * g + r];
        }
    }
    const float binf0 = binf[0];

    const int gwid = blockIdx.x * 4 + wib;
    const int nw   = gridDim.x * 4;

    for (int tile = gwid; tile < NE / 16; tile += nw) {
        const int eid = tile * 16 + e;
        const int sN = ei[eid];
        const int dN = ei[NE + eid];

        const float dx = x[dN * 3 + 0] - x[sN * 3 + 0];
        const float dy = x[dN * 3 + 1] - x[sN * 3 + 1];
        const float dz = x[dN * 3 + 2] - x[sN * 3 + 2];
        const float dsq = dx * dx + dy * dy + dz * dz;
        const float edis = sigmoidf_(TEMP / (sqrtf(dsq) + 1e-8f));

        bf16x8 B2[2];
        #pragma unroll
        for (int ks = 0; ks < 2; ++ks) {
            const uint4 ut = *(const uint4*)(Pt + (size_t)dN * 64 + 32 * ks + 8 * g);
            const uint4 ub = *(const uint4*)(Pb + (size_t)sN * 64 + 32 * ks + 8 * g);
            bf16x8 b;
            unsigned tw, bw;
            tw = ut.x; bw = ub.x;
            b[0] = f2bf(fmaxf(bf2f(tw & 0xffffu) + bf2f(bw & 0xffffu), 0.f));
            b[1] = f2bf(fmaxf(bf2f(tw >> 16)     + bf2f(bw >> 16),     0.f));
            tw = ut.y; bw = ub.y;
            b[2] = f2bf(fmaxf(bf2f(tw & 0xffffu) + bf2f(bw & 0xffffu), 0.f));
            b[3] = f2bf(fmaxf(bf2f(tw >> 16)     + bf2f(bw >> 16),     0.f));
            tw = ut.z; bw = ub.z;
            b[4] = f2bf(fmaxf(bf2f(tw & 0xffffu) + bf2f(bw & 0xffffu), 0.f));
            b[5] = f2bf(fmaxf(bf2f(tw >> 16)     + bf2f(bw >> 16),     0.f));
            tw = ut.w; bw = ub.w;
            b[6] = f2bf(fmaxf(bf2f(tw & 0xffffu) + bf2f(bw & 0xffffu), 0.f));
            b[7] = f2bf(fmaxf(bf2f(tw >> 16)     + bf2f(bw >> 16),     0.f));
            B2[ks] = b;
        }

        f32x4 acc2[4];
        #pragma unroll
        for (int t = 0; t < 4; ++t) {
            acc2[t] = b2r[t];
            #pragma unroll
            for (int ks = 0; ks < 2; ++ks)
                acc2[t] = __builtin_amdgcn_mfma_f32_16x16x32_bf16(A2[t][ks], B2[ks], acc2[t], 0, 0, 0);
        }

        float m[4][4];
        float p = 0.f;
        #pragma unroll
        for (int t = 0; t < 4; ++t)
            #pragma unroll
            for (int r = 0; r < 4; ++r) {
                m[t][r] = fmaxf(acc2[t][r], 0.f);
                p = fmaf(m[t][r], wir[t][r], p);
            }
        p += __shfl_xor(p, 16);
        p += __shfl_xor(p, 32);
        const float w = sigmoidf_((p + binf0) * edis);

        #pragma unroll
        for (int t = 0; t < 4; ++t)
            #pragma unroll
            for (int r = 0; r < 4; ++r)
                fb[e * 64 + ((16 * t + 4 * g + r) ^ se)] = m[t][r] * w;

        #pragma unroll
        for (int i = 0; i < 16; ++i) {
            const int row = __shfl(dN, i);
            const int si = ((i & 1) << 4) | ((i >> 1) & 3);
            const float v = fb[i * 64 + (lane ^ si)];
            atomicAdd(mi + (size_t)row * 64 + lane, v);
        }
    }
}

// ============ Node kernel: same B2B MFMA + residual + LayerNorm =============
extern "C" __global__ void __launch_bounds__(256, 2)
node_kernel(const float* __restrict__ h, const float* __restrict__ mi_,
            const float* __restrict__ Wn1, const float* __restrict__ bn1,
            const float* __restrict__ Wn2, const float* __restrict__ bn2,
            const float* __restrict__ lng, const float* __restrict__ lnb,
            float* __restrict__ out)
{
    __shared__ unsigned xlds[4][16 * 32];
    const int tid  = threadIdx.x;
    const int wib  = tid >> 6;
    const int lane = tid & 63;
    const int e = lane & 15, g = lane >> 4;
    unsigned* tb = &xlds[wib][0];
    const int sw = (e & 7) << 2;

    bf16x8 A1[4][4], A2[4][2];
    f32x4 b1r[4], b2r[4], gr[4], br[4];
    #pragma unroll
    for (int t = 0; t < 4; ++t) {
        #pragma unroll
        for (int ks = 0; ks < 4; ++ks) {
            bf16x8 a;
            #pragma unroll
            for (int j = 0; j < 8; ++j)
                a[j] = f2bf(Wn1[(32 * ks + 8 * g + j) * 64 + 16 * t + e]);
            A1[t][ks] = a;
        }
        #pragma unroll
        for (int ks = 0; ks < 2; ++ks) {
            bf16x8 a;
            #pragma unroll
            for (int j = 0; j < 8; ++j)
                a[j] = f2bf(Wn2[(32 * ks + 8 * g + j) * 64 + 16 * t + e]);
            A2[t][ks] = a;
        }
        #pragma unroll
        for (int r = 0; r < 4; ++r) {
            b1r[t][r] = bn1[16 * t + 4 * g + r];
            b2r[t][r] = bn2[16 * t + 4 * g + r];
            gr[t][r]  = lng[16 * t + 4 * g + r];
            br[t][r]  = lnb[16 * t + 4 * g + r];
        }
    }

    const int gwid = blockIdx.x * 4 + wib;
    const int nw   = gridDim.x * 4;

    for (int tile = gwid; tile < NN / 16; tile += nw) {
        const int node = tile * 16 + e;

        bf16x8 B1[4];
        #pragma unroll
        for (int ks = 0; ks < 4; ++ks) {
            const float* srcp = (ks < 2) ? mi_ : h;
            const float4* p = (const float4*)(srcp + (size_t)node * 64 + (ks & 1) * 32 + 8 * g);
            const float4 f0 = p[0], f1 = p[1];
            bf16x8 b;
            b[0] = f2bf(f0.x); b[1] = f2bf(f0.y); b[2] = f2bf(f0.z); b[3] = f2bf(f0.w);
            b[4] = f2bf(f1.x); b[5] = f2bf(f1.y); b[6] = f2bf(f1.z); b[7] = f2bf(f1.w);
            B1[ks] = b;
        }

        f32x4 acc1[4];
        #pragma unroll
        for (int t = 0; t < 4; ++t) {
            acc1[t] = b1r[t];
            #pragma unroll
            for (int ks = 0; ks < 4; ++ks)
                acc1[t] = __builtin_amdgcn_mfma_f32_16x16x32_bf16(A1[t][ks], B1[ks], acc1[t], 0, 0, 0);
        }

        #pragma unroll
        for (int t = 0; t < 4; ++t) {
            const float r0 = fmaxf(acc1[t][0], 0.f), r1 = fmaxf(acc1[t][1], 0.f);
            const float r2 = fmaxf(acc1[t][2], 0.f), r3 = fmaxf(acc1[t][3], 0.f);
            tb[e * 32 + ((8 * t + 2 * g + 0) ^ sw)] = pk2(r0, r1);
            tb[e * 32 + ((8 * t + 2 * g + 1) ^ sw)] = pk2(r2, r3);
        }
        bf16x8 B2[2];
        #pragma unroll
        for (int ks = 0; ks < 2; ++ks) {
            union { uint4 u; bf16x8 b; } cvt;
            cvt.u = *(const uint4*)&tb[e * 32 + ((16 * ks + 4 * g) ^ sw)];
            B2[ks] = cvt.b;
        }

        f32x4 acc2[4];
        #pragma unroll
        for (int t = 0; t < 4; ++t) {
            acc2[t] = b2r[t];
            #pragma unroll
            for (int ks = 0; ks < 2; ++ks)
                acc2[t] = __builtin_amdgcn_mfma_f32_16x16x32_bf16(A2[t][ks], B2[ks], acc2[t], 0, 0, 0);
        }

        float z[4][4];
        float s1 = 0.f, s2 = 0.f;
        #pragma unroll
        for (int t = 0; t < 4; ++t) {
            const float4 hres = *(const float4*)(h + (size_t)node * 64 + 16 * t + 4 * g);
            #pragma unroll
            for (int r = 0; r < 4; ++r) {
                z[t][r] = acc2[t][r] + hres[r];
                s1 += z[t][r];
                s2 = fmaf(z[t][r], z[t][r], s2);
            }
        }
        s1 += __shfl_xor(s1, 16); s1 += __shfl_xor(s1, 32);
        s2 += __shfl_xor(s2, 16); s2 += __shfl_xor(s2, 32);
        const float mu   = s1 * (1.0f / 64.0f);
        const float var  = s2 * (1.0f / 64.0f) - mu * mu;
        const float rstd = rsqrtf(var + LNEPS);

        #pragma unroll
        for (int t = 0; t < 4; ++t) {
            float4 o;
            #pragma unroll
            for (int r = 0; r < 4; ++r)
                o[r] = (z[t][r] - mu) * rstd * gr[t][r] + br[t][r];
            *(float4*)(out + (size_t)node * 64 + 16 * t + 4 * g) = o;
        }
    }
}

extern "C" void kernel_launch(void* const* d_in, const int* in_sizes, int n_in,
                              void* d_out, int out_size, void* d_ws, size_t ws_size,
                              hipStream_t stream)
{
    const float* h    = (const float*)d_in[0];
    const float* x    = (const float*)d_in[1];
    const int*   ei   = (const int*)d_in[2];
    const float* We1  = (const float*)d_in[3];
    const float* be1  = (const float*)d_in[4];
    const float* We2  = (const float*)d_in[5];
    const float* be2  = (const float*)d_in[6];
    const float* Winf = (const float*)d_in[7];
    const float* binf = (const float*)d_in[8];
    const float* Wn1  = (const float*)d_in[9];
    const float* bn1  = (const float*)d_in[10];
    const float* Wn2  = (const float*)d_in[11];
    const float* bn2  = (const float*)d_in[12];
    const float* lng  = (const float*)d_in[13];
    const float* lnb  = (const float*)d_in[14];
    float* out = (float*)d_out;

    const size_t mi_bytes  = (size_t)NN * HDIM * sizeof(float);          // 25.6 MB
    const size_t p_bytes   = (size_t)NN * HDIM * sizeof(unsigned short); // 12.8 MB
    const size_t sp_bytes  = (size_t)NE * sizeof(int2);                  // 12.8 MB
    const size_t cnt_bytes = (size_t)NN * sizeof(int);                   // 0.4 MB

    const size_t need_sorted = mi_bytes + 2 * p_bytes + sp_bytes + 2 * cnt_bytes;

    if (ws_size >= need_sorted) {
        char* ws = (char*)d_ws;
        float*          mi    = (float*)ws;                       ws += mi_bytes;
        unsigned short* Pt    = (unsigned short*)ws;              ws += p_bytes;
        unsigned short* Pb    = (unsigned short*)ws;              ws += p_bytes;
        int2*           spair = (int2*)ws;                        ws += sp_bytes;
        int*            cnt   = (int*)ws;                         ws += cnt_bytes;
        int*            cur   = (int*)ws;

        hipMemsetAsync(mi, 0, mi_bytes, stream);
        hipMemsetAsync(cnt, 0, cnt_bytes, stream);
        hipMemcpyAsync(out + (size_t)NN * HDIM, x, (size_t)NN * 3 * sizeof(float),
                       hipMemcpyDeviceToDevice, stream);

        hist_kernel<<<2048, 256, 0, stream>>>(ei, cnt);
        scan_kernel<<<1, 1024, 0, stream>>>(cnt, cur);
        scatter_kernel<<<2048, 256, 0, stream>>>(ei, cur, spair);
        pre_kernel<<<512, 256, 0, stream>>>(h, We1, be1, Pt, Pb);
        edge_kernel_sorted<<<2048, 256, 0, stream>>>(Pt, Pb, x, spair, We2, be2, Winf, binf, mi);
        node_kernel<<<512, 256, 0, stream>>>(h, mi, Wn1, bn1, Wn2, bn2, lng, lnb, out);
    } else {
        float* mi;
        unsigned short* Pt;
        unsigned short* Pb;
        if (ws_size >= mi_bytes + 2 * p_bytes) {
            mi = (float*)d_ws;
            Pt = (unsigned short*)((char*)d_ws + mi_bytes);
            Pb = (unsigned short*)((char*)d_ws + mi_bytes + p_bytes);
        } else {
            mi = out;
            Pt = (unsigned short*)d_ws;
            Pb = (unsigned short*)((char*)d_ws + p_bytes);
        }

        hipMemsetAsync(mi, 0, mi_bytes, stream);
        hipMemcpyAsync(out + (size_t)NN * HDIM, x, (size_t)NN * 3 * sizeof(float),
                       hipMemcpyDeviceToDevice, stream);

        pre_kernel<<<512, 256, 0, stream>>>(h, We1, be1, Pt, Pb);
        edge_kernel_unsorted<<<2048, 256, 0, stream>>>(Pt, Pb, x, ei, We2, be2, Winf, binf, mi);
        node_kernel<<<512, 256, 0, stream>>>(h, mi, Wn1, bn1, Wn2, bn2, lng, lnb, out);
    }
}

// Round 4
// 337.541 us; speedup vs baseline: 1.4422x; 1.4422x over previous
//
#include <hip/hip_runtime.h>
#include <hip/hip_bf16.h>
#include <math.h>

#define HDIM 64
#define NN   100000
#define NE   1600000
#define TEMP 30.0f
#define LNEPS 1e-5f

typedef __attribute__((ext_vector_type(8))) short bf16x8;
typedef __attribute__((ext_vector_type(4))) float f32x4;

__device__ __forceinline__ short f2bf(float f) {
    __hip_bfloat16 b = __float2bfloat16(f);
    short s; __builtin_memcpy(&s, &b, 2); return s;
}
__device__ __forceinline__ unsigned pk2(float lo, float hi) {
    return (unsigned)(unsigned short)f2bf(lo) | ((unsigned)(unsigned short)f2bf(hi) << 16);
}
__device__ __forceinline__ float bf2f(unsigned u) {
    union { unsigned u; float f; } c; c.u = u << 16; return c.f;
}
__device__ __forceinline__ float sigmoidf_(float z) { return 1.0f / (1.0f + __expf(-z)); }

// ============ Pre kernel: per-NODE factorization of edge GEMM1 ============
// e_in @ We1 = h[dst] @ We1[0:64] + h[src] @ We1[64:128]
// Pt[n] = h[n] @ We1_top + be1 ; Pb[n] = h[n] @ We1_bot   (bf16 rows, 128 B)
extern "C" __global__ void __launch_bounds__(256, 2)
pre_kernel(const float* __restrict__ h,
           const float* __restrict__ We1, const float* __restrict__ be1,
           unsigned short* __restrict__ Pt, unsigned short* __restrict__ Pb)
{
    __shared__ float fx[4][1024];
    const int tid  = threadIdx.x;
    const int wib  = tid >> 6;
    const int lane = tid & 63;
    const int e = lane & 15, g = lane >> 4;
    float* fb = &fx[wib][0];
    const int se = ((e & 1) << 4) | ((e >> 1) & 3);

    bf16x8 At[4][2], Ab[4][2];
    f32x4 b1r[4];
    #pragma unroll
    for (int t = 0; t < 4; ++t) {
        #pragma unroll
        for (int ks = 0; ks < 2; ++ks) {
            bf16x8 a, b;
            #pragma unroll
            for (int j = 0; j < 8; ++j) {
                a[j] = f2bf(We1[(32 * ks + 8 * g + j) * 64 + 16 * t + e]);
                b[j] = f2bf(We1[(64 + 32 * ks + 8 * g + j) * 64 + 16 * t + e]);
            }
            At[t][ks] = a; Ab[t][ks] = b;
        }
        #pragma unroll
        for (int r = 0; r < 4; ++r) b1r[t][r] = be1[16 * t + 4 * g + r];
    }

    const int gwid = blockIdx.x * 4 + wib;
    const int nw   = gridDim.x * 4;

    for (int tile = gwid; tile < NN / 16; tile += nw) {
        const int node = tile * 16 + e;

        bf16x8 B[2];
        #pragma unroll
        for (int ks = 0; ks < 2; ++ks) {
            const float4* p = (const float4*)(h + (size_t)node * 64 + ks * 32 + 8 * g);
            const float4 f0 = p[0], f1 = p[1];
            bf16x8 b;
            b[0] = f2bf(f0.x); b[1] = f2bf(f0.y); b[2] = f2bf(f0.z); b[3] = f2bf(f0.w);
            b[4] = f2bf(f1.x); b[5] = f2bf(f1.y); b[6] = f2bf(f1.z); b[7] = f2bf(f1.w);
            B[ks] = b;
        }

        f32x4 aT[4], aB[4];
        #pragma unroll
        for (int t = 0; t < 4; ++t) {
            aT[t] = b1r[t];
            aB[t] = (f32x4){0.f, 0.f, 0.f, 0.f};
            #pragma unroll
            for (int ks = 0; ks < 2; ++ks) {
                aT[t] = __builtin_amdgcn_mfma_f32_16x16x32_bf16(At[t][ks], B[ks], aT[t], 0, 0, 0);
                aB[t] = __builtin_amdgcn_mfma_f32_16x16x32_bf16(Ab[t][ks], B[ks], aB[t], 0, 0, 0);
            }
        }

        #pragma unroll
        for (int t = 0; t < 4; ++t)
            #pragma unroll
            for (int r = 0; r < 4; ++r)
                fb[e * 64 + ((16 * t + 4 * g + r) ^ se)] = aT[t][r];
        #pragma unroll
        for (int q = 0; q < 2; ++q) {
            const int row = q * 8 + (lane >> 3);
            const int sr  = ((row & 1) << 4) | ((row >> 1) & 3);
            const int c0  = (lane & 7) * 8;
            uint4 o;
            o.x = pk2(fb[row * 64 + ((c0 + 0) ^ sr)], fb[row * 64 + ((c0 + 1) ^ sr)]);
            o.y = pk2(fb[row * 64 + ((c0 + 2) ^ sr)], fb[row * 64 + ((c0 + 3) ^ sr)]);
            o.z = pk2(fb[row * 64 + ((c0 + 4) ^ sr)], fb[row * 64 + ((c0 + 5) ^ sr)]);
            o.w = pk2(fb[row * 64 + ((c0 + 6) ^ sr)], fb[row * 64 + ((c0 + 7) ^ sr)]);
            *(uint4*)((char*)Pt + (size_t)tile * 2048 + q * 1024 + lane * 16) = o;
        }

        #pragma unroll
        for (int t = 0; t < 4; ++t)
            #pragma unroll
            for (int r = 0; r < 4; ++r)
                fb[e * 64 + ((16 * t + 4 * g + r) ^ se)] = aB[t][r];
        #pragma unroll
        for (int q = 0; q < 2; ++q) {
            const int row = q * 8 + (lane >> 3);
            const int sr  = ((row & 1) << 4) | ((row >> 1) & 3);
            const int c0  = (lane & 7) * 8;
            uint4 o;
            o.x = pk2(fb[row * 64 + ((c0 + 0) ^ sr)], fb[row * 64 + ((c0 + 1) ^ sr)]);
            o.y = pk2(fb[row * 64 + ((c0 + 2) ^ sr)], fb[row * 64 + ((c0 + 3) ^ sr)]);
            o.z = pk2(fb[row * 64 + ((c0 + 4) ^ sr)], fb[row * 64 + ((c0 + 5) ^ sr)]);
            o.w = pk2(fb[row * 64 + ((c0 + 6) ^ sr)], fb[row * 64 + ((c0 + 7) ^ sr)]);
            *(uint4*)((char*)Pb + (size_t)tile * 2048 + q * 1024 + lane * 16) = o;
        }
    }
}

// ============ Counting-sort of edges by dst ============
extern "C" __global__ void __launch_bounds__(256)
hist_kernel(const int* __restrict__ ei, int* __restrict__ cnt)
{
    const int stride = gridDim.x * 256;
    for (int i = blockIdx.x * 256 + threadIdx.x; i < NE; i += stride)
        atomicAdd(&cnt[ei[NE + i]], 1);
}

// --- hierarchical exclusive scan of cnt[NN] -> cur[NN] (3 cheap launches) ---
#define SCAN_NB 98   // ceil(NN/1024)

extern "C" __global__ void __launch_bounds__(1024)
scan1_kernel(const int* __restrict__ cnt, int* __restrict__ cur, int* __restrict__ bsum)
{
    __shared__ int sh[1024];
    const int t = threadIdx.x;
    const int i = blockIdx.x * 1024 + t;
    const int v = (i < NN) ? cnt[i] : 0;
    sh[t] = v;
    __syncthreads();
    #pragma unroll
    for (int off = 1; off < 1024; off <<= 1) {
        const int u = (t >= off) ? sh[t - off] : 0;
        __syncthreads();
        sh[t] += u;
        __syncthreads();
    }
    if (i < NN) cur[i] = sh[t] - v;               // exclusive within block
    if (t == 1023) bsum[blockIdx.x] = sh[1023];   // block total
}

extern "C" __global__ void __launch_bounds__(128)
scan2_kernel(int* __restrict__ bsum)
{
    __shared__ int sh[128];
    const int t = threadIdx.x;
    const int v = (t < SCAN_NB) ? bsum[t] : 0;
    sh[t] = v;
    __syncthreads();
    #pragma unroll
    for (int off = 1; off < 128; off <<= 1) {
        const int u = (t >= off) ? sh[t - off] : 0;
        __syncthreads();
        sh[t] += u;
        __syncthreads();
    }
    if (t < SCAN_NB) bsum[t] = sh[t] - v;         // exclusive block offsets
}

extern "C" __global__ void __launch_bounds__(1024)
scan3_kernel(int* __restrict__ cur, const int* __restrict__ bsum)
{
    const int i = blockIdx.x * 1024 + threadIdx.x;
    if (i < NN) cur[i] += bsum[blockIdx.x];
}

extern "C" __global__ void __launch_bounds__(256)
scatter_kernel(const int* __restrict__ ei, int* __restrict__ cur,
               int2* __restrict__ spair)
{
    const int stride = gridDim.x * 256;
    for (int i = blockIdx.x * 256 + threadIdx.x; i < NE; i += stride) {
        const int s = ei[i];
        const int d = ei[NE + i];
        const int pos = atomicAdd(&cur[d], 1);
        spair[pos] = make_int2(s, d);
    }
}

// ============ Edge kernel (sorted): GEMM2 + gate + segmented reg-accumulate ====
// Edges sorted by dst; each wave walks a CONTIGUOUS chunk of 16-edge tiles,
// accumulating each node's output row in a register (channel = lane) and
// flushing ONE atomic row-write per distinct node (~106K flushes vs 1.6M).
extern "C" __global__ void __launch_bounds__(256, 2)
edge_kernel_sorted(const unsigned short* __restrict__ Pt, const unsigned short* __restrict__ Pb,
                   const float* __restrict__ x, const int2* __restrict__ spair,
                   const float* __restrict__ We2, const float* __restrict__ be2,
                   const float* __restrict__ Winf, const float* __restrict__ binf,
                   float* __restrict__ mi)
{
    __shared__ float fx[4][1024];
    const int tid  = threadIdx.x;
    const int wib  = tid >> 6;
    const int lane = tid & 63;
    const int e = lane & 15, g = lane >> 4;
    float* fb = &fx[wib][0];
    const int se = ((e & 1) << 4) | ((e >> 1) & 3);

    bf16x8 A2[4][2];
    f32x4 b2r[4], wir[4];
    #pragma unroll
    for (int t = 0; t < 4; ++t) {
        #pragma unroll
        for (int ks = 0; ks < 2; ++ks) {
            bf16x8 a;
            #pragma unroll
            for (int j = 0; j < 8; ++j)
                a[j] = f2bf(We2[(32 * ks + 8 * g + j) * 64 + 16 * t + e]);
            A2[t][ks] = a;
        }
        #pragma unroll
        for (int r = 0; r < 4; ++r) {
            b2r[t][r] = be2[16 * t + 4 * g + r];
            wir[t][r] = Winf[16 * t + 4 * g + r];
        }
    }
    const float binf0 = binf[0];

    const int NT     = NE / 16;
    const int nwaves = gridDim.x * 4;
    const int gwid   = blockIdx.x * 4 + wib;
    const int chunk  = (NT + nwaves - 1) / nwaves;
    const int t0 = gwid * chunk;
    const int t1 = (t0 + chunk < NT) ? t0 + chunk : NT;

    float racc  = 0.f;   // running row accumulator, channel = lane
    int   rrow  = -1;    // wave-uniform current node id

    for (int tile = t0; tile < t1; ++tile) {
        const int eid = tile * 16 + e;
        const int2 sd = spair[eid];
        const int sN = sd.x;
        const int dN = sd.y;

        const float dx = x[dN * 3 + 0] - x[sN * 3 + 0];
        const float dy = x[dN * 3 + 1] - x[sN * 3 + 1];
        const float dz = x[dN * 3 + 2] - x[sN * 3 + 2];
        const float dsq = dx * dx + dy * dy + dz * dz;
        const float edis = sigmoidf_(TEMP / (sqrtf(dsq) + 1e-8f));

        // ---- B2 frags: relu(Pt[dst] + Pb[src]) on k=32ks+8g+{0..7} ----
        bf16x8 B2[2];
        #pragma unroll
        for (int ks = 0; ks < 2; ++ks) {
            const uint4 ut = *(const uint4*)(Pt + (size_t)dN * 64 + 32 * ks + 8 * g);
            const uint4 ub = *(const uint4*)(Pb + (size_t)sN * 64 + 32 * ks + 8 * g);
            bf16x8 b;
            unsigned tw, bw;
            tw = ut.x; bw = ub.x;
            b[0] = f2bf(fmaxf(bf2f(tw & 0xffffu) + bf2f(bw & 0xffffu), 0.f));
            b[1] = f2bf(fmaxf(bf2f(tw >> 16)     + bf2f(bw >> 16),     0.f));
            tw = ut.y; bw = ub.y;
            b[2] = f2bf(fmaxf(bf2f(tw & 0xffffu) + bf2f(bw & 0xffffu), 0.f));
            b[3] = f2bf(fmaxf(bf2f(tw >> 16)     + bf2f(bw >> 16),     0.f));
            tw = ut.z; bw = ub.z;
            b[4] = f2bf(fmaxf(bf2f(tw & 0xffffu) + bf2f(bw & 0xffffu), 0.f));
            b[5] = f2bf(fmaxf(bf2f(tw >> 16)     + bf2f(bw >> 16),     0.f));
            tw = ut.w; bw = ub.w;
            b[6] = f2bf(fmaxf(bf2f(tw & 0xffffu) + bf2f(bw & 0xffffu), 0.f));
            b[7] = f2bf(fmaxf(bf2f(tw >> 16)     + bf2f(bw >> 16),     0.f));
            B2[ks] = b;
        }

        // ---- GEMM2 + bias ----
        f32x4 acc2[4];
        #pragma unroll
        for (int t = 0; t < 4; ++t) {
            acc2[t] = b2r[t];
            #pragma unroll
            for (int ks = 0; ks < 2; ++ks)
                acc2[t] = __builtin_amdgcn_mfma_f32_16x16x32_bf16(A2[t][ks], B2[ks], acc2[t], 0, 0, 0);
        }

        // ---- relu, edge_inf dot, gate ----
        float m[4][4];
        float p = 0.f;
        #pragma unroll
        for (int t = 0; t < 4; ++t)
            #pragma unroll
            for (int r = 0; r < 4; ++r) {
                m[t][r] = fmaxf(acc2[t][r], 0.f);
                p = fmaf(m[t][r], wir[t][r], p);
            }
        p += __shfl_xor(p, 16);
        p += __shfl_xor(p, 32);
        const float w = sigmoidf_((p + binf0) * edis);

        // ---- transpose m*w through LDS to [edge][channel] (bank-swizzled) ----
        #pragma unroll
        for (int t = 0; t < 4; ++t)
            #pragma unroll
            for (int r = 0; r < 4; ++r)
                fb[e * 64 + ((16 * t + 4 * g + r) ^ se)] = m[t][r] * w;

        // ---- segmented accumulate over sorted dst; flush once per run ----
        #pragma unroll
        for (int i = 0; i < 16; ++i) {
            const int row = __builtin_amdgcn_readlane(dN, i);   // wave-uniform (SGPR)
            const int si = ((i & 1) << 4) | ((i >> 1) & 3);
            const float v = fb[i * 64 + (lane ^ si)];
            if (row != rrow) {
                if (rrow >= 0) atomicAdd(mi + (size_t)rrow * 64 + lane, racc);
                rrow = row; racc = v;
            } else {
                racc += v;
            }
        }
    }
    if (rrow >= 0) atomicAdd(mi + (size_t)rrow * 64 + lane, racc);
}

// ============ Edge kernel (unsorted fallback, R2 path) ============
extern "C" __global__ void __launch_bounds__(256, 2)
edge_kernel_unsorted(const unsigned short* __restrict__ Pt, const unsigned short* __restrict__ Pb,
                     const float* __restrict__ x, const int* __restrict__ ei,
                     const float* __restrict__ We2, const float* __restrict__ be2,
                     const float* __restrict__ Winf, const float* __restrict__ binf,
                     float* __restrict__ mi)
{
    __shared__ float fx[4][1024];
    const int tid  = threadIdx.x;
    const int wib  = tid >> 6;
    const int lane = tid & 63;
    const int e = lane & 15, g = lane >> 4;
    float* fb = &fx[wib][0];
    const int se = ((e & 1) << 4) | ((e >> 1) & 3);

    bf16x8 A2[4][2];
    f32x4 b2r[4], wir[4];
    #pragma unroll
    for (int t = 0; t < 4; ++t) {
        #pragma unroll
        for (int ks = 0; ks < 2; ++ks) {
            bf16x8 a;
            #pragma unroll
            for (int j = 0; j < 8; ++j)
                a[j] = f2bf(We2[(32 * ks + 8 * g + j) * 64 + 16 * t + e]);
            A2[t][ks] = a;
        }
        #pragma unroll
        for (int r = 0; r < 4; ++r) {
            b2r[t][r] = be2[16 * t + 4 * g + r];
            wir[t][r] = Winf[16 * t + 4 * g + r];
        }
    }
    const float binf0 = binf[0];

    const int gwid = blockIdx.x * 4 + wib;
    const int nw   = gridDim.x * 4;

    for (int tile = gwid; tile < NE / 16; tile += nw) {
        const int eid = tile * 16 + e;
        const int sN = ei[eid];
        const int dN = ei[NE + eid];

        const float dx = x[dN * 3 + 0] - x[sN * 3 + 0];
        const float dy = x[dN * 3 + 1] - x[sN * 3 + 1];
        const float dz = x[dN * 3 + 2] - x[sN * 3 + 2];
        const float dsq = dx * dx + dy * dy + dz * dz;
        const float edis = sigmoidf_(TEMP / (sqrtf(dsq) + 1e-8f));

        bf16x8 B2[2];
        #pragma unroll
        for (int ks = 0; ks < 2; ++ks) {
            const uint4 ut = *(const uint4*)(Pt + (size_t)dN * 64 + 32 * ks + 8 * g);
            const uint4 ub = *(const uint4*)(Pb + (size_t)sN * 64 + 32 * ks + 8 * g);
            bf16x8 b;
            unsigned tw, bw;
            tw = ut.x; bw = ub.x;
            b[0] = f2bf(fmaxf(bf2f(tw & 0xffffu) + bf2f(bw & 0xffffu), 0.f));
            b[1] = f2bf(fmaxf(bf2f(tw >> 16)     + bf2f(bw >> 16),     0.f));
            tw = ut.y; bw = ub.y;
            b[2] = f2bf(fmaxf(bf2f(tw & 0xffffu) + bf2f(bw & 0xffffu), 0.f));
            b[3] = f2bf(fmaxf(bf2f(tw >> 16)     + bf2f(bw >> 16),     0.f));
            tw = ut.z; bw = ub.z;
            b[4] = f2bf(fmaxf(bf2f(tw & 0xffffu) + bf2f(bw & 0xffffu), 0.f));
            b[5] = f2bf(fmaxf(bf2f(tw >> 16)     + bf2f(bw >> 16),     0.f));
            tw = ut.w; bw = ub.w;
            b[6] = f2bf(fmaxf(bf2f(tw & 0xffffu) + bf2f(bw & 0xffffu), 0.f));
            b[7] = f2bf(fmaxf(bf2f(tw >> 16)     + bf2f(bw >> 16),     0.f));
            B2[ks] = b;
        }

        f32x4 acc2[4];
        #pragma unroll
        for (int t = 0; t < 4; ++t) {
            acc2[t] = b2r[t];
            #pragma unroll
            for (int ks = 0; ks < 2; ++ks)
                acc2[t] = __builtin_amdgcn_mfma_f32_16x16x32_bf16(A2[t][ks], B2[ks], acc2[t], 0, 0, 0);
        }

        float m[4][4];
        float p = 0.f;
        #pragma unroll
        for (int t = 0; t < 4; ++t)
            #pragma unroll
            for (int r = 0; r < 4; ++r) {
                m[t][r] = fmaxf(acc2[t][r], 0.f);
                p = fmaf(m[t][r], wir[t][r], p);
            }
        p += __shfl_xor(p, 16);
        p += __shfl_xor(p, 32);
        const float w = sigmoidf_((p + binf0) * edis);

        #pragma unroll
        for (int t = 0; t < 4; ++t)
            #pragma unroll
            for (int r = 0; r < 4; ++r)
                fb[e * 64 + ((16 * t + 4 * g + r) ^ se)] = m[t][r] * w;

        #pragma unroll
        for (int i = 0; i < 16; ++i) {
            const int row = __shfl(dN, i);
            const int si = ((i & 1) << 4) | ((i >> 1) & 3);
            const float v = fb[i * 64 + (lane ^ si)];
            atomicAdd(mi + (size_t)row * 64 + lane, v);
        }
    }
}

// ============ Node kernel: same B2B MFMA + residual + LayerNorm =============
extern "C" __global__ void __launch_bounds__(256, 2)
node_kernel(const float* __restrict__ h, const float* __restrict__ mi_,
            const float* __restrict__ Wn1, const float* __restrict__ bn1,
            const float* __restrict__ Wn2, const float* __restrict__ bn2,
            const float* __restrict__ lng, const float* __restrict__ lnb,
            float* __restrict__ out)
{
    __shared__ unsigned xlds[4][16 * 32];
    const int tid  = threadIdx.x;
    const int wib  = tid >> 6;
    const int lane = tid & 63;
    const int e = lane & 15, g = lane >> 4;
    unsigned* tb = &xlds[wib][0];
    const int sw = (e & 7) << 2;

    bf16x8 A1[4][4], A2[4][2];
    f32x4 b1r[4], b2r[4], gr[4], br[4];
    #pragma unroll
    for (int t = 0; t < 4; ++t) {
        #pragma unroll
        for (int ks = 0; ks < 4; ++ks) {
            bf16x8 a;
            #pragma unroll
            for (int j = 0; j < 8; ++j)
                a[j] = f2bf(Wn1[(32 * ks + 8 * g + j) * 64 + 16 * t + e]);
            A1[t][ks] = a;
        }
        #pragma unroll
        for (int ks = 0; ks < 2; ++ks) {
            bf16x8 a;
            #pragma unroll
            for (int j = 0; j < 8; ++j)
                a[j] = f2bf(Wn2[(32 * ks + 8 * g + j) * 64 + 16 * t + e]);
            A2[t][ks] = a;
        }
        #pragma unroll
        for (int r = 0; r < 4; ++r) {
            b1r[t][r] = bn1[16 * t + 4 * g + r];
            b2r[t][r] = bn2[16 * t + 4 * g + r];
            gr[t][r]  = lng[16 * t + 4 * g + r];
            br[t][r]  = lnb[16 * t + 4 * g + r];
        }
    }

    const int gwid = blockIdx.x * 4 + wib;
    const int nw   = gridDim.x * 4;

    for (int tile = gwid; tile < NN / 16; tile += nw) {
        const int node = tile * 16 + e;

        bf16x8 B1[4];
        #pragma unroll
        for (int ks = 0; ks < 4; ++ks) {
            const float* srcp = (ks < 2) ? mi_ : h;
            const float4* p = (const float4*)(srcp + (size_t)node * 64 + (ks & 1) * 32 + 8 * g);
            const float4 f0 = p[0], f1 = p[1];
            bf16x8 b;
            b[0] = f2bf(f0.x); b[1] = f2bf(f0.y); b[2] = f2bf(f0.z); b[3] = f2bf(f0.w);
            b[4] = f2bf(f1.x); b[5] = f2bf(f1.y); b[6] = f2bf(f1.z); b[7] = f2bf(f1.w);
            B1[ks] = b;
        }

        f32x4 acc1[4];
        #pragma unroll
        for (int t = 0; t < 4; ++t) {
            acc1[t] = b1r[t];
            #pragma unroll
            for (int ks = 0; ks < 4; ++ks)
                acc1[t] = __builtin_amdgcn_mfma_f32_16x16x32_bf16(A1[t][ks], B1[ks], acc1[t], 0, 0, 0);
        }

        #pragma unroll
        for (int t = 0; t < 4; ++t) {
            const float r0 = fmaxf(acc1[t][0], 0.f), r1 = fmaxf(acc1[t][1], 0.f);
            const float r2 = fmaxf(acc1[t][2], 0.f), r3 = fmaxf(acc1[t][3], 0.f);
            tb[e * 32 + ((8 * t + 2 * g + 0) ^ sw)] = pk2(r0, r1);
            tb[e * 32 + ((8 * t + 2 * g + 1) ^ sw)] = pk2(r2, r3);
        }
        bf16x8 B2[2];
        #pragma unroll
        for (int ks = 0; ks < 2; ++ks) {
            union { uint4 u; bf16x8 b; } cvt;
            cvt.u = *(const uint4*)&tb[e * 32 + ((16 * ks + 4 * g) ^ sw)];
            B2[ks] = cvt.b;
        }

        f32x4 acc2[4];
        #pragma unroll
        for (int t = 0; t < 4; ++t) {
            acc2[t] = b2r[t];
            #pragma unroll
            for (int ks = 0; ks < 2; ++ks)
                acc2[t] = __builtin_amdgcn_mfma_f32_16x16x32_bf16(A2[t][ks], B2[ks], acc2[t], 0, 0, 0);
        }

        float z[4][4];
        float s1 = 0.f, s2 = 0.f;
        #pragma unroll
        for (int t = 0; t < 4; ++t) {
            const float4 hres = *(const float4*)(h + (size_t)node * 64 + 16 * t + 4 * g);
            #pragma unroll
            for (int r = 0; r < 4; ++r) {
                z[t][r] = acc2[t][r] + hres[r];
                s1 += z[t][r];
                s2 = fmaf(z[t][r], z[t][r], s2);
            }
        }
        s1 += __shfl_xor(s1, 16); s1 += __shfl_xor(s1, 32);
        s2 += __shfl_xor(s2, 16); s2 += __shfl_xor(s2, 32);
        const float mu   = s1 * (1.0f / 64.0f);
        const float var  = s2 * (1.0f / 64.0f) - mu * mu;
        const float rstd = rsqrtf(var + LNEPS);

        #pragma unroll
        for (int t = 0; t < 4; ++t) {
            float4 o;
            #pragma unroll
            for (int r = 0; r < 4; ++r)
                o[r] = (z[t][r] - mu) * rstd * gr[t][r] + br[t][r];
            *(float4*)(out + (size_t)node * 64 + 16 * t + 4 * g) = o;
        }
    }
}

extern "C" void kernel_launch(void* const* d_in, const int* in_sizes, int n_in,
                              void* d_out, int out_size, void* d_ws, size_t ws_size,
                              hipStream_t stream)
{
    const float* h    = (const float*)d_in[0];
    const float* x    = (const float*)d_in[1];
    const int*   ei   = (const int*)d_in[2];
    const float* We1  = (const float*)d_in[3];
    const float* be1  = (const float*)d_in[4];
    const float* We2  = (const float*)d_in[5];
    const float* be2  = (const float*)d_in[6];
    const float* Winf = (const float*)d_in[7];
    const float* binf = (const float*)d_in[8];
    const float* Wn1  = (const float*)d_in[9];
    const float* bn1  = (const float*)d_in[10];
    const float* Wn2  = (const float*)d_in[11];
    const float* bn2  = (const float*)d_in[12];
    const float* lng  = (const float*)d_in[13];
    const float* lnb  = (const float*)d_in[14];
    float* out = (float*)d_out;

    const size_t mi_bytes  = (size_t)NN * HDIM * sizeof(float);          // 25.6 MB
    const size_t p_bytes   = (size_t)NN * HDIM * sizeof(unsigned short); // 12.8 MB
    const size_t sp_bytes  = (size_t)NE * sizeof(int2);                  // 12.8 MB
    const size_t cnt_bytes = (size_t)NN * sizeof(int);                   // 0.4 MB
    const size_t bs_bytes  = 128 * sizeof(int);

    const size_t need_sorted = mi_bytes + 2 * p_bytes + sp_bytes + 2 * cnt_bytes + bs_bytes;

    if (ws_size >= need_sorted) {
        char* ws = (char*)d_ws;
        float*          mi    = (float*)ws;                       ws += mi_bytes;
        unsigned short* Pt    = (unsigned short*)ws;              ws += p_bytes;
        unsigned short* Pb    = (unsigned short*)ws;              ws += p_bytes;
        int2*           spair = (int2*)ws;                        ws += sp_bytes;
        int*            cnt   = (int*)ws;                         ws += cnt_bytes;
        int*            cur   = (int*)ws;                         ws += cnt_bytes;
        int*            bsum  = (int*)ws;

        hipMemsetAsync(mi, 0, mi_bytes, stream);
        hipMemsetAsync(cnt, 0, cnt_bytes, stream);
        hipMemcpyAsync(out + (size_t)NN * HDIM, x, (size_t)NN * 3 * sizeof(float),
                       hipMemcpyDeviceToDevice, stream);

        hist_kernel<<<2048, 256, 0, stream>>>(ei, cnt);
        scan1_kernel<<<SCAN_NB, 1024, 0, stream>>>(cnt, cur, bsum);
        scan2_kernel<<<1, 128, 0, stream>>>(bsum);
        scan3_kernel<<<SCAN_NB, 1024, 0, stream>>>(cur, bsum);
        scatter_kernel<<<2048, 256, 0, stream>>>(ei, cur, spair);
        pre_kernel<<<512, 256, 0, stream>>>(h, We1, be1, Pt, Pb);
        edge_kernel_sorted<<<2048, 256, 0, stream>>>(Pt, Pb, x, spair, We2, be2, Winf, binf, mi);
        node_kernel<<<512, 256, 0, stream>>>(h, mi, Wn1, bn1, Wn2, bn2, lng, lnb, out);
    } else {
        float* mi;
        unsigned short* Pt;
        unsigned short* Pb;
        if (ws_size >= mi_bytes + 2 * p_bytes) {
            mi = (float*)d_ws;
            Pt = (unsigned short*)((char*)d_ws + mi_bytes);
            Pb = (unsigned short*)((char*)d_ws + mi_bytes + p_bytes);
        } else {
            mi = out;
            Pt = (unsigned short*)d_ws;
            Pb = (unsigned short*)((char*)d_ws + p_bytes);
        }

        hipMemsetAsync(mi, 0, mi_bytes, stream);
        hipMemcpyAsync(out + (size_t)NN * HDIM, x, (size_t)NN * 3 * sizeof(float),
                       hipMemcpyDeviceToDevice, stream);

        pre_kernel<<<512, 256, 0, stream>>>(h, We1, be1, Pt, Pb);
        edge_kernel_unsorted<<<2048, 256, 0, stream>>>(Pt, Pb, x, ei, We2, be2, Winf, binf, mi);
        node_kernel<<<512, 256, 0, stream>>>(h, mi, Wn1, bn1, Wn2, bn2, lng, lnb, out);
    }
}